// Round 4
// baseline (107.279 us; speedup 1.0000x reference)
//
#include <hip/hip_runtime.h>
#include <hip/hip_bf16.h>

// ROC-AUC loss via Fourier CDF approximation. Two launches:
// k_detect (64 blocks):  dtype-detect targets (u8-bool / i32 / f32) via byte-OR
//                        (per-block OR word); zero replica accumulators + ticket.
// k_main  (1024 blocks): masked sums of sin/cos(2*pi*k*s), k=1..128, pos-class
//                        and total (neg = total - pos). CHUNK=256 staged in LDS
//                        as float2(score,mask); 1 harmonic per thread (x2 halves);
//                        hw v_sin/v_cos in revolutions: sin(2pi*k*s)=v_sin(fract(k*s)).
//                        Block results atomicAdd'ed into 1-of-8 replica rows.
//                        LAST block (device-scope ticket, no spin -> no
//                        co-residency assumption) re-reads replicas with
//                        agent-scope atomic loads and computes integrated coeffs,
//                        normalized CDFs at 1024 thresholds, Riemann AUC -> out.

#define NK 128
#define NSTEPS 1024
#define K1_TPB 256
#define CHUNK 256
#define REP 8
#define RSTRIDE 520          // floats per replica row: 512 sums + count + pad
#define ZTOT (REP * RSTRIDE + 16)  // zeroed region incl. ticket word
#define DET_BLOCKS 64
#define DET_TPB 256

__device__ __forceinline__ float wave_sum(float v) {
  #pragma unroll
  for (int off = 32; off > 0; off >>= 1) v += __shfl_down(v, off, 64);
  return v;
}

// Block-reduce to thread 0. scratch >= blockDim/64 floats.
__device__ __forceinline__ float block_sum(float v, float* scratch) {
  int lane = threadIdx.x & 63, wid = threadIdx.x >> 6;
  v = wave_sum(v);
  if (lane == 0) scratch[wid] = v;
  __syncthreads();
  float r = 0.0f;
  if (threadIdx.x == 0) {
    int nw = blockDim.x >> 6;
    for (int w = 0; w < nw; ++w) r += scratch[w];
  }
  return r;
}

// ---- dtype detect (per-block OR word) + zero replicas/ticket ----
// Scans only the first N BYTES (in-bounds under every dtype interpretation).
// i32 {0,1} -> only byte-lane0 set ; u8 {0,1} -> multiple byte lanes set ;
// f32 {0.0,1.0} -> 0x3F800000 (lanes 2,3). All-zero -> mode 0 (all masks decode
// to 0 under any true dtype -> identical result).
__global__ __launch_bounds__(DET_TPB) void k_detect(const unsigned char* __restrict__ t,
                                                    int nbytes,
                                                    unsigned* __restrict__ flags,
                                                    float* __restrict__ acc) {
  __shared__ unsigned s_or;
  const int gid = blockIdx.x * DET_TPB + threadIdx.x;
  if (threadIdx.x == 0) s_or = 0u;
  for (int i = gid; i < ZTOT; i += DET_BLOCKS * DET_TPB) acc[i] = 0.0f;
  __syncthreads();
  unsigned local = 0u;
  int n16 = nbytes >> 4;
  const uint4* p = (const uint4*)t;
  for (int i = gid; i < n16; i += DET_BLOCKS * DET_TPB) {
    uint4 v = p[i];
    local |= v.x | v.y | v.z | v.w;
  }
  if (gid < (nbytes & 15)) {            // tail bytes (gid<16 lives in block 0)
    int i = (n16 << 4) + gid;
    local |= ((unsigned)t[i]) << ((i & 3) * 8);
  }
  if (local) atomicOr(&s_or, local);
  __syncthreads();
  if (threadIdx.x == 0) flags[blockIdx.x] = s_or;
}

__device__ __forceinline__ int decode_mode(const unsigned* __restrict__ flags) {
  unsigned o = 0u;
  #pragma unroll
  for (int i = 0; i < DET_BLOCKS; ++i) o |= flags[i];   // uniform -> scalar loads
  if (o == 0u) return 0;
  bool nz0 = (o & 0xFFu) != 0u;
  bool nz1 = (o & 0xFF00u) != 0u;
  if (!nz1 && !(o & 0xFFFF0000u)) return 1;  // int32 values {0,1}
  if (!nz0 && !nz1) return 2;                // float32 values {0.0,1.0}
  return 0;                                  // uint8 / bool
}

// LDS is phase-exclusive: partial phase uses .p, final phase (last block, after
// __syncthreads) uses .f. All cross-phase data lives in global `acc`.
union SharedB {
  struct { float2 d[CHUNK]; float comb[NK * 4]; } p;
  struct {
    float sums[NK * 4];
    float isp[NK], icp[NK], isn[NK], icn[NK];
    float pn[NSTEPS + 2], nn[NSTEPS + 2];
    float npos;
  } f;
};

__global__ __launch_bounds__(K1_TPB) void k_main(const float* __restrict__ scores,
                                                 const unsigned char* __restrict__ tgt,
                                                 int N,
                                                 const unsigned* __restrict__ flags,
                                                 float* __restrict__ acc,
                                                 unsigned* __restrict__ ticket,
                                                 float* __restrict__ out) {
  __shared__ SharedB sh;
  __shared__ float s_red[K1_TPB / 64];
  __shared__ int s_mode;
  __shared__ int s_last;
  const int tid = threadIdx.x;
  if (tid == 0) s_mode = decode_mode(flags);
  __syncthreads();
  const int mode = s_mode;
  const int base = blockIdx.x * CHUNK;

  // ---- stage one sample per thread ----
  float m = 0.0f;
  {
    int g = base + tid;
    float s = 0.0f;
    if (g < N) {
      s = scores[g];
      if (mode == 0)      m = (float)tgt[g];
      else if (mode == 1) m = (float)((const int*)tgt)[g];
      else                m = ((const float*)tgt)[g];
    }
    sh.p.d[tid] = make_float2(s, m);
  }
  __syncthreads();
  float cnt = block_sum(m, s_red);  // valid on thread 0 only

  // ---- masked Fourier sums: 1 harmonic per thread, 2 chunk-halves ----
  const int k_idx = tid & (NK - 1);
  const int half = tid >> 7;          // 0 or 1
  const float kf = (float)(k_idx + 1);
  const int HC = CHUNK / 2;           // 128 samples per half
  const int i0 = half * HC;

  float ps0 = 0.f, pc0 = 0.f, ts0 = 0.f, tc0 = 0.f;
  float ps1 = 0.f, pc1 = 0.f, ts1 = 0.f, tc1 = 0.f;
  for (int i = 0; i < HC; i += 8) {
    float2 r[8];
    #pragma unroll
    for (int j = 0; j < 8; ++j) r[j] = sh.p.d[i0 + i + j];  // b128 broadcast reads
    #pragma unroll
    for (int j = 0; j < 8; ++j) {
      float x = kf * r[j].x;
      float f = __builtin_amdgcn_fractf(x);      // k*s mod 1 (revolutions)
      float sn = __builtin_amdgcn_sinf(f);       // sin(2*pi*k*s)
      float cs = __builtin_amdgcn_cosf(f);       // cos(2*pi*k*s)
      if (j & 1) {
        ts1 += sn; tc1 += cs;
        ps1 = fmaf(r[j].y, sn, ps1); pc1 = fmaf(r[j].y, cs, pc1);
      } else {
        ts0 += sn; tc0 += cs;
        ps0 = fmaf(r[j].y, sn, ps0); pc0 = fmaf(r[j].y, cs, pc0);
      }
    }
  }
  float ps = ps0 + ps1, pc = pc0 + pc1, ts = ts0 + ts1, tc = tc0 + tc1;
  // padded (g>=N) entries have s=0,m=0 -> contributed cos(0)=1 to tc only; remove
  int valid = min(max(N - base - i0, 0), HC);
  tc -= (float)(HC - valid);

  if (half == 1) {
    sh.p.comb[k_idx * 4 + 0] = ps;
    sh.p.comb[k_idx * 4 + 1] = pc;
    sh.p.comb[k_idx * 4 + 2] = ts;
    sh.p.comb[k_idx * 4 + 3] = tc;
  }
  __syncthreads();
  float* ab = acc + (size_t)(blockIdx.x & (REP - 1)) * RSTRIDE;
  if (half == 0) {
    atomicAdd(&ab[k_idx * 4 + 0], ps + sh.p.comb[k_idx * 4 + 0]);
    atomicAdd(&ab[k_idx * 4 + 1], pc + sh.p.comb[k_idx * 4 + 1]);
    atomicAdd(&ab[k_idx * 4 + 2], ts + sh.p.comb[k_idx * 4 + 2]);
    atomicAdd(&ab[k_idx * 4 + 3], tc + sh.p.comb[k_idx * 4 + 3]);
  }
  if (tid == 0) atomicAdd(&ab[NK * 4], cnt);

  // ---- last-block ticket (no spin: every other block simply retires) ----
  __syncthreads();  // barrier semantics drain each wave's outstanding atomics
  if (tid == 0) {
    __threadfence();
    unsigned r = __hip_atomic_fetch_add(ticket, 1u, __ATOMIC_ACQ_REL,
                                        __HIP_MEMORY_SCOPE_AGENT);
    s_last = (r == (unsigned)(gridDim.x - 1)) ? 1 : 0;
  }
  __syncthreads();
  if (!s_last) return;

  // ================= final phase: last block only =================
  // agent-scope atomic loads: replicas were written by atomics (coherence
  // point); avoid any possibility of a stale local-L2 line.
  for (int q = tid; q < NK * 4; q += K1_TPB) {
    float v = 0.0f;
    #pragma unroll
    for (int r = 0; r < REP; ++r)
      v += __hip_atomic_load(&acc[r * RSTRIDE + q], __ATOMIC_RELAXED,
                             __HIP_MEMORY_SCOPE_AGENT);
    sh.f.sums[q] = v;
  }
  if (tid == 0) {
    float v = 0.0f;
    #pragma unroll
    for (int r = 0; r < REP; ++r)
      v += __hip_atomic_load(&acc[r * RSTRIDE + NK * 4], __ATOMIC_RELAXED,
                             __HIP_MEMORY_SCOPE_AGENT);
    sh.f.npos = v;
  }
  __syncthreads();

  // integrated Fourier coefficients for both classes
  if (tid < NK) {
    const float eps = 1.1920929e-07f;  // FLT_EPSILON = jnp.finfo(f32).eps
    float npos = sh.f.npos;
    float nneg = (float)N - npos;
    float sp = sh.f.sums[tid * 4 + 0], cp = sh.f.sums[tid * 4 + 1];
    float st = sh.f.sums[tid * 4 + 2], ct = sh.f.sums[tid * 4 + 3];
    float scp, ccp, scn, ccn;
    if (npos < eps) { scp = 0.0f; ccp = 0.0f; }
    else { float d = fmaxf(npos, eps); scp = sp / d; ccp = cp / d; }
    if (nneg < eps) { scn = 0.0f; ccn = 0.0f; }
    else { float d = fmaxf(nneg, eps); scn = (st - sp) / d; ccn = (ct - cp) / d; }
    float w = 6.2831853071795864769f * (float)(tid + 1);  // fl(2*pi)*k, as ref
    sh.f.isp[tid] = ccp / w;  sh.f.icp[tid] = -scp / w;
    sh.f.isn[tid] = ccn / w;  sh.f.icn[tid] = -scn / w;
  }
  __syncthreads();

  // normalized CDFs at 1024 thresholds: 4 per thread, k-major for trans ILP
  {
    float th[4], cp_[4] = {0, 0, 0, 0}, cn_[4] = {0, 0, 0, 0};
    #pragma unroll
    for (int q = 0; q < 4; ++q) th[q] = (float)(tid + q * K1_TPB) * (1.0f / 1023.0f);
    for (int k = 0; k < NK; ++k) {
      float isp = sh.f.isp[k], icp = sh.f.icp[k];
      float isn = sh.f.isn[k], icn = sh.f.icn[k];
      float kf1 = (float)(k + 1);
      #pragma unroll
      for (int q = 0; q < 4; ++q) {
        float f = __builtin_amdgcn_fractf(kf1 * th[q]);
        float sn = __builtin_amdgcn_sinf(f);
        float cs = __builtin_amdgcn_cosf(f);
        cp_[q] = fmaf(sn, isp, fmaf(cs, icp, cp_[q]));
        cn_[q] = fmaf(sn, isn, fmaf(cs, icn, cn_[q]));
      }
    }
    #pragma unroll
    for (int q = 0; q < 4; ++q) {
      int t = tid + q * K1_TPB;
      sh.f.pn[t + 1] = 1.0f - 0.5f * (cp_[q] + 0.5f);
      sh.f.nn[t + 1] = 1.0f - 0.5f * (cn_[q] + 0.5f);
    }
  }
  if (tid == 0) {
    sh.f.pn[0] = 1.0f; sh.f.nn[0] = 1.0f;
    sh.f.pn[NSTEPS + 1] = 0.0f; sh.f.nn[NSTEPS + 1] = 0.0f;
  }
  __syncthreads();

  // Riemann AUC both directions
  float pa = 0.0f, na = 0.0f;
  for (int i = tid; i < NSTEPS + 1; i += K1_TPB) {
    float p0 = sh.f.pn[i], p1 = sh.f.pn[i + 1];
    float n0 = sh.f.nn[i], n1 = sh.f.nn[i + 1];
    pa = fmaf(p0, n0 - n1, pa);   // pos_norm[i] * (-diff(neg_norm))[i]
    na = fmaf(n0, p1 - p0, na);   // neg_norm[i] * diff(pos_norm)[i]
  }
  float paS = block_sum(pa, s_red);
  __syncthreads();
  float naS = block_sum(na, s_red);
  if (tid == 0) out[0] = 0.5f * (paS + (1.0f + naS));
}

extern "C" void kernel_launch(void* const* d_in, const int* in_sizes, int n_in,
                              void* d_out, int out_size, void* d_ws, size_t ws_size,
                              hipStream_t stream) {
  const float* scores = (const float*)d_in[0];
  const unsigned char* targets = (const unsigned char*)d_in[1];
  const int N = in_sizes[0];

  unsigned* flags = (unsigned*)d_ws;                 // 64 words
  float* acc = (float*)((char*)d_ws + 512);          // ZTOT floats (zeroed by A)
  unsigned* ticket = (unsigned*)(acc + REP * RSTRIDE);  // inside zeroed region

  const int nblocks = (N + CHUNK - 1) / CHUNK;       // 1024 for N=262144

  k_detect<<<DET_BLOCKS, DET_TPB, 0, stream>>>(targets, N, flags, acc);
  k_main<<<nblocks, K1_TPB, 0, stream>>>(scores, targets, N, flags, acc, ticket,
                                         (float*)d_out);
}

// Round 5
// 99.092 us; speedup vs baseline: 1.0826x; 1.0826x over previous
//
#include <hip/hip_runtime.h>
#include <hip/hip_bf16.h>

// ROC-AUC loss via Fourier CDF approximation. Three launches (R3 structure —
// the R4 fused-finale experiment regressed; see journal):
// k_detect (64 blocks):  dtype-detect targets (u8-bool / i32 / f32) via byte-OR
//                        (per-block OR word); zero the replica accumulators.
// k_partial (2048 blocks, CHUNK=128): masked sums of sin/cos(2*pi*k*s), k=1..128,
//                        pos-class and total (neg = total - pos). Chunk in LDS as
//                        float2(score,mask); 1 harmonic per thread (x2 halves);
//                        hw v_sin/v_cos in revolutions: sin(2pi*k*s)=v_sin(fract(k*s)).
//                        32 waves/CU (full occupancy) to keep the quarter-rate
//                        trans pipe fed. Block sums atomicAdd into 1-of-16 replica
//                        rows (per-address atomic depth 128).
// k_final  (1 block, 1024 thr): sum replicas, integrated Fourier coeffs,
//                        normalized CDFs at 1024 thresholds (k-major, 4 thr/thread
//                        for trans ILP), Riemann AUC, write scalar.

#define NK 128
#define NSTEPS 1024
#define K1_TPB 256
#define CHUNK 128
#define REP 16
#define RSTRIDE 520          // floats per replica row: 512 sums + count + pad
#define ZTOT (REP * RSTRIDE)
#define DET_BLOCKS 64
#define DET_TPB 256
#define K2_TPB 1024

__device__ __forceinline__ float wave_sum(float v) {
  #pragma unroll
  for (int off = 32; off > 0; off >>= 1) v += __shfl_down(v, off, 64);
  return v;
}

// Block-reduce to thread 0. scratch >= blockDim/64 floats.
__device__ __forceinline__ float block_sum(float v, float* scratch) {
  int lane = threadIdx.x & 63, wid = threadIdx.x >> 6;
  v = wave_sum(v);
  if (lane == 0) scratch[wid] = v;
  __syncthreads();
  float r = 0.0f;
  if (threadIdx.x == 0) {
    int nw = blockDim.x >> 6;
    for (int w = 0; w < nw; ++w) r += scratch[w];
  }
  return r;
}

// ---- dtype detect (per-block OR word) + zero replicas ----
// Scans only the first N BYTES (in-bounds under every dtype interpretation).
// i32 {0,1} -> only byte-lane0 set ; u8 {0,1} -> multiple byte lanes set ;
// f32 {0.0,1.0} -> 0x3F800000 (lanes 2,3). All-zero -> mode 0 (all masks decode
// to 0 under any true dtype -> identical result).
__global__ __launch_bounds__(DET_TPB) void k_detect(const unsigned char* __restrict__ t,
                                                    int nbytes,
                                                    unsigned* __restrict__ flags,
                                                    float* __restrict__ acc) {
  __shared__ unsigned s_or;
  const int gid = blockIdx.x * DET_TPB + threadIdx.x;
  if (threadIdx.x == 0) s_or = 0u;
  for (int i = gid; i < ZTOT; i += DET_BLOCKS * DET_TPB) acc[i] = 0.0f;
  __syncthreads();
  unsigned local = 0u;
  int n16 = nbytes >> 4;
  const uint4* p = (const uint4*)t;
  for (int i = gid; i < n16; i += DET_BLOCKS * DET_TPB) {
    uint4 v = p[i];
    local |= v.x | v.y | v.z | v.w;
  }
  if (gid < (nbytes & 15)) {            // tail bytes (gid<16 lives in block 0)
    int i = (n16 << 4) + gid;
    local |= ((unsigned)t[i]) << ((i & 3) * 8);
  }
  if (local) atomicOr(&s_or, local);
  __syncthreads();
  if (threadIdx.x == 0) flags[blockIdx.x] = s_or;
}

__device__ __forceinline__ int decode_or(unsigned o) {
  if (o == 0u) return 0;
  bool nz0 = (o & 0xFFu) != 0u;
  bool nz1 = (o & 0xFF00u) != 0u;
  if (!nz1 && !(o & 0xFFFF0000u)) return 1;  // int32 values {0,1}
  if (!nz0 && !nz1) return 2;                // float32 values {0.0,1.0}
  return 0;                                  // uint8 / bool
}

// ---- phase 1: masked Fourier sums, atomically accumulated into replicas ----
__global__ __launch_bounds__(K1_TPB) void k_partial(const float* __restrict__ scores,
                                                    const unsigned char* __restrict__ tgt,
                                                    int N,
                                                    const unsigned* __restrict__ flags,
                                                    float* __restrict__ acc) {
  __shared__ float2 s_d[CHUNK];       // (score, mask)
  __shared__ float s_comb[NK * 4];    // half==1 partials for combine
  __shared__ float s_red[K1_TPB / 64];
  __shared__ int s_mode;
  const int tid = threadIdx.x;
  // wave 0: parallel OR-reduce of the 64 flag words, 6 shuffles
  if (tid < 64) {
    unsigned o = flags[tid];
    #pragma unroll
    for (int off = 32; off > 0; off >>= 1) o |= __shfl_xor(o, off, 64);
    if (tid == 0) s_mode = decode_or(o);
  }
  const int base = blockIdx.x * CHUNK;
  __syncthreads();
  const int mode = s_mode;

  // stage one sample per thread (first CHUNK threads)
  float m = 0.0f;
  if (tid < CHUNK) {
    int g = base + tid;
    float s = 0.0f;
    if (g < N) {
      s = scores[g];
      if (mode == 0)      m = (float)tgt[g];
      else if (mode == 1) m = (float)((const int*)tgt)[g];
      else                m = ((const float*)tgt)[g];
    }
    s_d[tid] = make_float2(s, m);
  }
  __syncthreads();
  float cnt = block_sum(m, s_red);  // valid on thread 0 only

  const int k_idx = tid & (NK - 1);
  const int half = tid >> 7;          // 0 or 1
  const float kf = (float)(k_idx + 1);
  const int HC = CHUNK / 2;           // 64 samples per half
  const int i0 = half * HC;

  float ps0 = 0.f, pc0 = 0.f, ts0 = 0.f, tc0 = 0.f;
  float ps1 = 0.f, pc1 = 0.f, ts1 = 0.f, tc1 = 0.f;
  for (int i = 0; i < HC; i += 8) {
    float2 r[8];
    #pragma unroll
    for (int j = 0; j < 8; ++j) r[j] = s_d[i0 + i + j];  // b128 broadcast reads
    #pragma unroll
    for (int j = 0; j < 8; ++j) {
      float x = kf * r[j].x;
      float f = __builtin_amdgcn_fractf(x);      // k*s mod 1 (revolutions)
      float sn = __builtin_amdgcn_sinf(f);       // sin(2*pi*k*s)
      float cs = __builtin_amdgcn_cosf(f);       // cos(2*pi*k*s)
      if (j & 1) {
        ts1 += sn; tc1 += cs;
        ps1 = fmaf(r[j].y, sn, ps1); pc1 = fmaf(r[j].y, cs, pc1);
      } else {
        ts0 += sn; tc0 += cs;
        ps0 = fmaf(r[j].y, sn, ps0); pc0 = fmaf(r[j].y, cs, pc0);
      }
    }
  }
  float ps = ps0 + ps1, pc = pc0 + pc1, ts = ts0 + ts1, tc = tc0 + tc1;
  // padded (g>=N) entries have s=0,m=0 -> contributed cos(0)=1 to tc only; remove
  int valid = min(max(N - base - i0, 0), HC);
  tc -= (float)(HC - valid);

  if (half == 1) {
    s_comb[k_idx * 4 + 0] = ps;
    s_comb[k_idx * 4 + 1] = pc;
    s_comb[k_idx * 4 + 2] = ts;
    s_comb[k_idx * 4 + 3] = tc;
  }
  __syncthreads();
  float* ab = acc + (size_t)(blockIdx.x & (REP - 1)) * RSTRIDE;
  if (half == 0) {
    atomicAdd(&ab[k_idx * 4 + 0], ps + s_comb[k_idx * 4 + 0]);
    atomicAdd(&ab[k_idx * 4 + 1], pc + s_comb[k_idx * 4 + 1]);
    atomicAdd(&ab[k_idx * 4 + 2], ts + s_comb[k_idx * 4 + 2]);
    atomicAdd(&ab[k_idx * 4 + 3], tc + s_comb[k_idx * 4 + 3]);
  }
  if (tid == 0) atomicAdd(&ab[NK * 4], cnt);
}

// ---- phase 2: sum replicas, coefficients, CDF eval, AUC ----
__global__ __launch_bounds__(K2_TPB) void k_final(const float* __restrict__ acc,
                                                  int N,
                                                  float* __restrict__ out) {
  __shared__ float s_sums[NK * 4];
  __shared__ float s_isp[NK], s_icp[NK], s_isn[NK], s_icn[NK];
  __shared__ float s_pn[NSTEPS + 2], s_nn[NSTEPS + 2];
  __shared__ float s_red[K2_TPB / 64];
  __shared__ float s_npos;
  const int tid = threadIdx.x;

  if (tid < NK * 4) {
    float v = 0.0f;
    #pragma unroll
    for (int r = 0; r < REP; ++r) v += acc[r * RSTRIDE + tid];
    s_sums[tid] = v;
  }
  if (tid == 0) {
    float v = 0.0f;
    #pragma unroll
    for (int r = 0; r < REP; ++r) v += acc[r * RSTRIDE + NK * 4];
    s_npos = v;
  }
  __syncthreads();

  // integrated Fourier coefficients for both classes
  if (tid < NK) {
    const float eps = 1.1920929e-07f;  // FLT_EPSILON = jnp.finfo(f32).eps
    float npos = s_npos;
    float nneg = (float)N - npos;
    float sp = s_sums[tid * 4 + 0], cp = s_sums[tid * 4 + 1];
    float st = s_sums[tid * 4 + 2], ct = s_sums[tid * 4 + 3];
    float scp, ccp, scn, ccn;
    if (npos < eps) { scp = 0.0f; ccp = 0.0f; }
    else { float d = fmaxf(npos, eps); scp = sp / d; ccp = cp / d; }
    if (nneg < eps) { scn = 0.0f; ccn = 0.0f; }
    else { float d = fmaxf(nneg, eps); scn = (st - sp) / d; ccn = (ct - cp) / d; }
    float w = 6.2831853071795864769f * (float)(tid + 1);  // fl(2*pi)*k, as ref
    s_isp[tid] = ccp / w;  s_icp[tid] = -scp / w;
    s_isn[tid] = ccn / w;  s_icn[tid] = -scn / w;
  }
  __syncthreads();

  // normalized CDFs at 1024 thresholds: 1 per thread, k-major with paired
  // accumulators for trans ILP
  {
    float thr = (float)tid * (1.0f / 1023.0f);
    float cpA = 0.f, cpB = 0.f, cnA = 0.f, cnB = 0.f;
    #pragma unroll 4
    for (int k = 0; k < NK; k += 2) {
      float fA = __builtin_amdgcn_fractf((float)(k + 1) * thr);
      float fB = __builtin_amdgcn_fractf((float)(k + 2) * thr);
      float snA = __builtin_amdgcn_sinf(fA);
      float snB = __builtin_amdgcn_sinf(fB);
      float csA = __builtin_amdgcn_cosf(fA);
      float csB = __builtin_amdgcn_cosf(fB);
      cpA = fmaf(snA, s_isp[k], fmaf(csA, s_icp[k], cpA));
      cnA = fmaf(snA, s_isn[k], fmaf(csA, s_icn[k], cnA));
      cpB = fmaf(snB, s_isp[k + 1], fmaf(csB, s_icp[k + 1], cpB));
      cnB = fmaf(snB, s_isn[k + 1], fmaf(csB, s_icn[k + 1], cnB));
    }
    s_pn[tid + 1] = 1.0f - 0.5f * ((cpA + cpB) + 0.5f);
    s_nn[tid + 1] = 1.0f - 0.5f * ((cnA + cnB) + 0.5f);
  }
  if (tid == 0) {
    s_pn[0] = 1.0f; s_nn[0] = 1.0f;
    s_pn[NSTEPS + 1] = 0.0f; s_nn[NSTEPS + 1] = 0.0f;
  }
  __syncthreads();

  // Riemann AUC both directions
  float pa = 0.0f, na = 0.0f;
  for (int i = tid; i < NSTEPS + 1; i += K2_TPB) {
    float p0 = s_pn[i], p1 = s_pn[i + 1];
    float n0 = s_nn[i], n1 = s_nn[i + 1];
    pa = fmaf(p0, n0 - n1, pa);   // pos_norm[i] * (-diff(neg_norm))[i]
    na = fmaf(n0, p1 - p0, na);   // neg_norm[i] * diff(pos_norm)[i]
  }
  float paS = block_sum(pa, s_red);
  __syncthreads();
  float naS = block_sum(na, s_red);
  if (tid == 0) out[0] = 0.5f * (paS + (1.0f + naS));
}

extern "C" void kernel_launch(void* const* d_in, const int* in_sizes, int n_in,
                              void* d_out, int out_size, void* d_ws, size_t ws_size,
                              hipStream_t stream) {
  const float* scores = (const float*)d_in[0];
  const unsigned char* targets = (const unsigned char*)d_in[1];
  const int N = in_sizes[0];

  unsigned* flags = (unsigned*)d_ws;                 // 64 words
  float* acc = (float*)((char*)d_ws + 512);          // ZTOT floats (zeroed by A)

  const int nblocks = (N + CHUNK - 1) / CHUNK;       // 2048 for N=262144

  k_detect<<<DET_BLOCKS, DET_TPB, 0, stream>>>(targets, N, flags, acc);
  k_partial<<<nblocks, K1_TPB, 0, stream>>>(scores, targets, N, flags, acc);
  k_final<<<1, K2_TPB, 0, stream>>>(acc, N, (float*)d_out);
}

// Round 6
// 91.653 us; speedup vs baseline: 1.1705x; 1.0812x over previous
//
#include <hip/hip_runtime.h>
#include <hip/hip_bf16.h>

// ROC-AUC loss via Fourier CDF approximation. Three launches.
// Geometry locked to the measured optimum (R3: CHUNK=256, REP=8, 1024 blocks;
// R5's 2048-block variant cost +5us in block-fixed overhead, R4's fused-finale
// cost +13us in ticket/tail overhead).
// k_detect (64 blocks):  dtype-detect targets (u8-bool / i32 / f32) via byte-OR
//                        (per-block OR word); zero the replica accumulators.
// k_partial (1024 blocks, CHUNK=256): masked sums of sin/cos(2*pi*k*s), k=1..128,
//                        pos-class and total (neg = total - pos). Chunk in LDS as
//                        float2(score,mask); 1 harmonic per thread (x2 halves);
//                        hw v_sin/v_cos in revolutions: sin(2pi*k*s)=v_sin(fract(k*s)).
//                        8 blocks/CU = 32 waves/CU (full occupancy). Block sums
//                        atomicAdd into 1-of-8 replica rows (atomic depth 128).
// k_final  (1 block, 1024 thr): sum replicas, integrated Fourier coeffs,
//                        normalized CDFs at 1024 thresholds (k-major 2-way ILP),
//                        Riemann AUC, write scalar.

#define NK 128
#define NSTEPS 1024
#define K1_TPB 256
#define CHUNK 256
#define REP 8
#define RSTRIDE 520          // floats per replica row: 512 sums + count + pad
#define ZTOT (REP * RSTRIDE)
#define DET_BLOCKS 64
#define DET_TPB 256
#define K2_TPB 1024

__device__ __forceinline__ float wave_sum(float v) {
  #pragma unroll
  for (int off = 32; off > 0; off >>= 1) v += __shfl_down(v, off, 64);
  return v;
}

// Block-reduce to thread 0. scratch >= blockDim/64 floats.
__device__ __forceinline__ float block_sum(float v, float* scratch) {
  int lane = threadIdx.x & 63, wid = threadIdx.x >> 6;
  v = wave_sum(v);
  if (lane == 0) scratch[wid] = v;
  __syncthreads();
  float r = 0.0f;
  if (threadIdx.x == 0) {
    int nw = blockDim.x >> 6;
    for (int w = 0; w < nw; ++w) r += scratch[w];
  }
  return r;
}

// ---- dtype detect (per-block OR word) + zero replicas ----
// Scans only the first N BYTES (in-bounds under every dtype interpretation).
// i32 {0,1} -> only byte-lane0 set ; u8 {0,1} -> multiple byte lanes set ;
// f32 {0.0,1.0} -> 0x3F800000 (lanes 2,3). All-zero -> mode 0 (all masks decode
// to 0 under any true dtype -> identical result).
__global__ __launch_bounds__(DET_TPB) void k_detect(const unsigned char* __restrict__ t,
                                                    int nbytes,
                                                    unsigned* __restrict__ flags,
                                                    float* __restrict__ acc) {
  __shared__ unsigned s_or;
  const int gid = blockIdx.x * DET_TPB + threadIdx.x;
  if (threadIdx.x == 0) s_or = 0u;
  for (int i = gid; i < ZTOT; i += DET_BLOCKS * DET_TPB) acc[i] = 0.0f;
  __syncthreads();
  unsigned local = 0u;
  int n16 = nbytes >> 4;
  const uint4* p = (const uint4*)t;
  for (int i = gid; i < n16; i += DET_BLOCKS * DET_TPB) {
    uint4 v = p[i];
    local |= v.x | v.y | v.z | v.w;
  }
  if (gid < (nbytes & 15)) {            // tail bytes (gid<16 lives in block 0)
    int i = (n16 << 4) + gid;
    local |= ((unsigned)t[i]) << ((i & 3) * 8);
  }
  if (local) atomicOr(&s_or, local);
  __syncthreads();
  if (threadIdx.x == 0) flags[blockIdx.x] = s_or;
}

__device__ __forceinline__ int decode_or(unsigned o) {
  if (o == 0u) return 0;
  bool nz0 = (o & 0xFFu) != 0u;
  bool nz1 = (o & 0xFF00u) != 0u;
  if (!nz1 && !(o & 0xFFFF0000u)) return 1;  // int32 values {0,1}
  if (!nz0 && !nz1) return 2;                // float32 values {0.0,1.0}
  return 0;                                  // uint8 / bool
}

// ---- phase 1: masked Fourier sums, atomically accumulated into replicas ----
__global__ __launch_bounds__(K1_TPB) void k_partial(const float* __restrict__ scores,
                                                    const unsigned char* __restrict__ tgt,
                                                    int N,
                                                    const unsigned* __restrict__ flags,
                                                    float* __restrict__ acc) {
  __shared__ float2 s_d[CHUNK];       // (score, mask)
  __shared__ float s_comb[NK * 4];    // half==1 partials for combine
  __shared__ float s_red[K1_TPB / 64];
  __shared__ int s_mode;
  const int tid = threadIdx.x;
  // wave 0: parallel OR-reduce of the 64 flag words, 6 shuffles
  if (tid < 64) {
    unsigned o = flags[tid];
    #pragma unroll
    for (int off = 32; off > 0; off >>= 1) o |= __shfl_xor(o, off, 64);
    if (tid == 0) s_mode = decode_or(o);
  }
  const int base = blockIdx.x * CHUNK;
  __syncthreads();
  const int mode = s_mode;

  // stage one sample per thread
  float m = 0.0f;
  {
    int g = base + tid;
    float s = 0.0f;
    if (g < N) {
      s = scores[g];
      if (mode == 0)      m = (float)tgt[g];
      else if (mode == 1) m = (float)((const int*)tgt)[g];
      else                m = ((const float*)tgt)[g];
    }
    s_d[tid] = make_float2(s, m);
  }
  __syncthreads();
  float cnt = block_sum(m, s_red);  // valid on thread 0 only

  const int k_idx = tid & (NK - 1);
  const int half = tid >> 7;          // 0 or 1
  const float kf = (float)(k_idx + 1);
  const int HC = CHUNK / 2;           // 128 samples per half
  const int i0 = half * HC;

  float ps0 = 0.f, pc0 = 0.f, ts0 = 0.f, tc0 = 0.f;
  float ps1 = 0.f, pc1 = 0.f, ts1 = 0.f, tc1 = 0.f;
  for (int i = 0; i < HC; i += 8) {
    float2 r[8];
    #pragma unroll
    for (int j = 0; j < 8; ++j) r[j] = s_d[i0 + i + j];  // b128 broadcast reads
    #pragma unroll
    for (int j = 0; j < 8; ++j) {
      float x = kf * r[j].x;
      float f = __builtin_amdgcn_fractf(x);      // k*s mod 1 (revolutions)
      float sn = __builtin_amdgcn_sinf(f);       // sin(2*pi*k*s)
      float cs = __builtin_amdgcn_cosf(f);       // cos(2*pi*k*s)
      if (j & 1) {
        ts1 += sn; tc1 += cs;
        ps1 = fmaf(r[j].y, sn, ps1); pc1 = fmaf(r[j].y, cs, pc1);
      } else {
        ts0 += sn; tc0 += cs;
        ps0 = fmaf(r[j].y, sn, ps0); pc0 = fmaf(r[j].y, cs, pc0);
      }
    }
  }
  float ps = ps0 + ps1, pc = pc0 + pc1, ts = ts0 + ts1, tc = tc0 + tc1;
  // padded (g>=N) entries have s=0,m=0 -> contributed cos(0)=1 to tc only; remove
  int valid = min(max(N - base - i0, 0), HC);
  tc -= (float)(HC - valid);

  if (half == 1) {
    s_comb[k_idx * 4 + 0] = ps;
    s_comb[k_idx * 4 + 1] = pc;
    s_comb[k_idx * 4 + 2] = ts;
    s_comb[k_idx * 4 + 3] = tc;
  }
  __syncthreads();
  float* ab = acc + (size_t)(blockIdx.x & (REP - 1)) * RSTRIDE;
  if (half == 0) {
    atomicAdd(&ab[k_idx * 4 + 0], ps + s_comb[k_idx * 4 + 0]);
    atomicAdd(&ab[k_idx * 4 + 1], pc + s_comb[k_idx * 4 + 1]);
    atomicAdd(&ab[k_idx * 4 + 2], ts + s_comb[k_idx * 4 + 2]);
    atomicAdd(&ab[k_idx * 4 + 3], tc + s_comb[k_idx * 4 + 3]);
  }
  if (tid == 0) atomicAdd(&ab[NK * 4], cnt);
}

// ---- phase 2: sum replicas, coefficients, CDF eval, AUC ----
__global__ __launch_bounds__(K2_TPB) void k_final(const float* __restrict__ acc,
                                                  int N,
                                                  float* __restrict__ out) {
  __shared__ float s_sums[NK * 4];
  __shared__ float s_isp[NK], s_icp[NK], s_isn[NK], s_icn[NK];
  __shared__ float s_pn[NSTEPS + 2], s_nn[NSTEPS + 2];
  __shared__ float s_red[K2_TPB / 64];
  __shared__ float s_npos;
  const int tid = threadIdx.x;

  if (tid < NK * 4) {
    float v = 0.0f;
    #pragma unroll
    for (int r = 0; r < REP; ++r) v += acc[r * RSTRIDE + tid];
    s_sums[tid] = v;
  }
  if (tid == 0) {
    float v = 0.0f;
    #pragma unroll
    for (int r = 0; r < REP; ++r) v += acc[r * RSTRIDE + NK * 4];
    s_npos = v;
  }
  __syncthreads();

  // integrated Fourier coefficients for both classes
  if (tid < NK) {
    const float eps = 1.1920929e-07f;  // FLT_EPSILON = jnp.finfo(f32).eps
    float npos = s_npos;
    float nneg = (float)N - npos;
    float sp = s_sums[tid * 4 + 0], cp = s_sums[tid * 4 + 1];
    float st = s_sums[tid * 4 + 2], ct = s_sums[tid * 4 + 3];
    float scp, ccp, scn, ccn;
    if (npos < eps) { scp = 0.0f; ccp = 0.0f; }
    else { float d = fmaxf(npos, eps); scp = sp / d; ccp = cp / d; }
    if (nneg < eps) { scn = 0.0f; ccn = 0.0f; }
    else { float d = fmaxf(nneg, eps); scn = (st - sp) / d; ccn = (ct - cp) / d; }
    float w = 6.2831853071795864769f * (float)(tid + 1);  // fl(2*pi)*k, as ref
    s_isp[tid] = ccp / w;  s_icp[tid] = -scp / w;
    s_isn[tid] = ccn / w;  s_icn[tid] = -scn / w;
  }
  __syncthreads();

  // normalized CDFs at 1024 thresholds: 1 per thread, k-major with paired
  // accumulators for trans-pipe ILP
  {
    float thr = (float)tid * (1.0f / 1023.0f);
    float cpA = 0.f, cpB = 0.f, cnA = 0.f, cnB = 0.f;
    #pragma unroll 4
    for (int k = 0; k < NK; k += 2) {
      float fA = __builtin_amdgcn_fractf((float)(k + 1) * thr);
      float fB = __builtin_amdgcn_fractf((float)(k + 2) * thr);
      float snA = __builtin_amdgcn_sinf(fA);
      float snB = __builtin_amdgcn_sinf(fB);
      float csA = __builtin_amdgcn_cosf(fA);
      float csB = __builtin_amdgcn_cosf(fB);
      cpA = fmaf(snA, s_isp[k], fmaf(csA, s_icp[k], cpA));
      cnA = fmaf(snA, s_isn[k], fmaf(csA, s_icn[k], cnA));
      cpB = fmaf(snB, s_isp[k + 1], fmaf(csB, s_icp[k + 1], cpB));
      cnB = fmaf(snB, s_isn[k + 1], fmaf(csB, s_icn[k + 1], cnB));
    }
    s_pn[tid + 1] = 1.0f - 0.5f * ((cpA + cpB) + 0.5f);
    s_nn[tid + 1] = 1.0f - 0.5f * ((cnA + cnB) + 0.5f);
  }
  if (tid == 0) {
    s_pn[0] = 1.0f; s_nn[0] = 1.0f;
    s_pn[NSTEPS + 1] = 0.0f; s_nn[NSTEPS + 1] = 0.0f;
  }
  __syncthreads();

  // Riemann AUC both directions
  float pa = 0.0f, na = 0.0f;
  for (int i = tid; i < NSTEPS + 1; i += K2_TPB) {
    float p0 = s_pn[i], p1 = s_pn[i + 1];
    float n0 = s_nn[i], n1 = s_nn[i + 1];
    pa = fmaf(p0, n0 - n1, pa);   // pos_norm[i] * (-diff(neg_norm))[i]
    na = fmaf(n0, p1 - p0, na);   // neg_norm[i] * diff(pos_norm)[i]
  }
  float paS = block_sum(pa, s_red);
  __syncthreads();
  float naS = block_sum(na, s_red);
  if (tid == 0) out[0] = 0.5f * (paS + (1.0f + naS));
}

extern "C" void kernel_launch(void* const* d_in, const int* in_sizes, int n_in,
                              void* d_out, int out_size, void* d_ws, size_t ws_size,
                              hipStream_t stream) {
  const float* scores = (const float*)d_in[0];
  const unsigned char* targets = (const unsigned char*)d_in[1];
  const int N = in_sizes[0];

  unsigned* flags = (unsigned*)d_ws;                 // 64 words
  float* acc = (float*)((char*)d_ws + 512);          // ZTOT floats (zeroed by A)

  const int nblocks = (N + CHUNK - 1) / CHUNK;       // 1024 for N=262144

  k_detect<<<DET_BLOCKS, DET_TPB, 0, stream>>>(targets, N, flags, acc);
  k_partial<<<nblocks, K1_TPB, 0, stream>>>(scores, targets, N, flags, acc);
  k_final<<<1, K2_TPB, 0, stream>>>(acc, N, (float*)d_out);
}